// Round 5
// baseline (36.815 us; speedup 1.0000x reference)
//
#include <hip/hip_runtime.h>

// MeanPooling: xs [B=16, T=2048, D=1024] fp32, xs_len [B] (int64 or int32), out [B, D] fp32.
// out[b][d] = sum_{t < len_b} xs[b][t][d] / len_b
//
// Three-phase, no atomics, no memset, proportional load balancing with
// PRECOMPUTED per-block descriptors (rounds 3/4 lesson: per-block partition
// math = serial preamble latency on every block; hoist it into one tiny
// setup dispatch).
//
//   setup: computes total = sum(len_b); cnt_b = ceil(len_b*NB/total);
//          prefix; packs (b, r0, r1) -> u32 desc per K1 block into ws table;
//          also (s0, cnt, len) per sample for K2.
//   K1:    block i: desc = table[i] (one load); streams rows [r0, r1) of
//          sample b into ws slot i. ~total/NB rows per block -> balanced.
//   K2:    block (b, c): reduces slots [s0, s0+cnt) for D-chunk c, scales
//          by 1/len, writes out.

#define B_ 16
#define T_ 2048
#define D_ 1024
#define NB 1024             // target active blocks in K1
#define NGRID (NB + B_)     // 1040: cnt sum <= NB + B_
#define TAB2 2048           // u32 index of per-sample table (s0, cnt, len, pad)
#define SLOT0_F4 1024       // float4 offset of partial-sum slots (16 KiB table area)

__device__ __forceinline__ int load_len(const void* p, bool is64, int k)
{
    long long len = is64 ? ((const long long*)p)[k]
                         : (long long)((const int*)p)[k];
    if (len < 1) len = 1;
    if (len > T_) len = T_;
    return (int)len;
}

__device__ __forceinline__ bool sniff64(const void* p)
{
    // int64 storage: element 0 read as i64 is in [1, T_]. int32 storage:
    // the i64 read = len0 | (len1 << 32) >= 2^32 since len1 >= 1.
    const long long v0 = ((const long long*)p)[0];
    return (v0 >= 1 && v0 <= (long long)T_);
}

// desc = (b << 23) | (r0 << 12) | r1 ; inactive = 0xFFFFFFFF
__device__ __forceinline__ unsigned compute_desc(
    int bid, const void* len_ptr, bool is64, unsigned total)
{
    int b = -1, j = 0, len = 1, cb = 1;
    unsigned p = 0;
    #pragma unroll
    for (int k = 0; k < B_; ++k) {
        const int lk = load_len(len_ptr, is64, k);
        const int ck = (int)(((unsigned)lk * NB + total - 1u) / total);  // >= 1
        const bool hit = (b < 0) && ((unsigned)bid < p + (unsigned)ck);
        if (hit) { b = k; j = bid - (int)p; len = lk; cb = ck; }
        p += (unsigned)ck;
    }
    if (b < 0) return 0xFFFFFFFFu;
    const unsigned r0 = ((unsigned)j * (unsigned)len) / (unsigned)cb;
    const unsigned r1 = ((unsigned)(j + 1) * (unsigned)len) / (unsigned)cb;
    if (r0 >= r1) return 0xFFFFFFFFu;
    return ((unsigned)b << 23) | (r0 << 12) | r1;
}

__global__ __launch_bounds__(1024) void mp_setup(
    const void* __restrict__ len_ptr,
    unsigned* __restrict__ table)
{
    const int tid = threadIdx.x;
    const bool is64 = sniff64(len_ptr);

    unsigned total = 0;
    #pragma unroll
    for (int k = 0; k < B_; ++k) total += (unsigned)load_len(len_ptr, is64, k);

    table[tid] = compute_desc(tid, len_ptr, is64, total);
    if (tid < B_) {
        table[NB + tid] = compute_desc(NB + tid, len_ptr, is64, total);

        // per-sample (s0, cnt, len) for K2
        unsigned p = 0;
        int s0 = 0, cb = 1, len = 1;
        #pragma unroll
        for (int k = 0; k < B_; ++k) {
            const int lk = load_len(len_ptr, is64, k);
            const int ck = (int)(((unsigned)lk * NB + total - 1u) / total);
            if (k == tid) { s0 = (int)p; cb = ck; len = lk; }
            p += (unsigned)ck;
        }
        table[TAB2 + 4 * tid + 0] = (unsigned)s0;
        table[TAB2 + 4 * tid + 1] = (unsigned)cb;
        table[TAB2 + 4 * tid + 2] = (unsigned)len;
    }
}

__global__ __launch_bounds__(256) void mp_partial(
    const float* __restrict__ xs,
    const unsigned* __restrict__ table,
    float* __restrict__ ws4)    // float4 base
{
    const unsigned desc = table[blockIdx.x];
    if (desc == 0xFFFFFFFFu) return;

    const int b  = (int)(desc >> 23);
    const int r0 = (int)((desc >> 12) & 0x7FFu);
    const int r1 = (int)(desc & 0xFFFu);

    const int tid = threadIdx.x;     // 256 threads x float4 = full 1024-wide D row

    const float4* src = (const float4*)0 + 0;  // silence unused warn pattern
    src = ((const float4*)xs) + ((long)b * T_ + r0) * (D_ / 4) + tid;
    float4 acc = make_float4(0.f, 0.f, 0.f, 0.f);

    #pragma unroll 4
    for (int t = r0; t < r1; ++t) {
        float4 v = *src;
        src += (D_ / 4);
        acc.x += v.x; acc.y += v.y; acc.z += v.z; acc.w += v.w;
    }

    ((float4*)ws4)[SLOT0_F4 + (long)blockIdx.x * (D_ / 4) + tid] = acc;
}

__global__ __launch_bounds__(256) void mp_reduce(
    const float* __restrict__ ws,
    const unsigned* __restrict__ table,
    float* __restrict__ out)
{
    const int b = blockIdx.x >> 2;   // 4 blocks per sample
    const int c = blockIdx.x & 3;    // D-chunk: 256 floats = 64 float4
    const int lane = threadIdx.x & 63;
    const int w = threadIdx.x >> 6;  // 4 waves stride the slots

    const int s0  = (int)table[TAB2 + 4 * b + 0];
    const int cb  = (int)table[TAB2 + 4 * b + 1];
    const int len = (int)table[TAB2 + 4 * b + 2];

    const int d4 = c * 64 + lane;    // float4 index in [0, 256)
    const float4* wsp = (const float4*)ws;

    float4 acc = make_float4(0.f, 0.f, 0.f, 0.f);
    for (int s = s0 + w; s < s0 + cb; s += 4) {
        float4 v = wsp[SLOT0_F4 + (long)s * (D_ / 4) + d4];
        acc.x += v.x; acc.y += v.y; acc.z += v.z; acc.w += v.w;
    }

    __shared__ float4 sm[4][64];
    sm[w][lane] = acc;
    __syncthreads();

    if (w == 0) {
        float4 a0 = sm[0][lane], a1 = sm[1][lane], a2 = sm[2][lane], a3 = sm[3][lane];
        const float inv = 1.0f / (float)len;
        float4 r;
        r.x = (a0.x + a1.x + a2.x + a3.x) * inv;
        r.y = (a0.y + a1.y + a2.y + a3.y) * inv;
        r.z = (a0.z + a1.z + a2.z + a3.z) * inv;
        r.w = (a0.w + a1.w + a2.w + a3.w) * inv;
        ((float4*)out)[(long)b * (D_ / 4) + d4] = r;
    }
}

extern "C" void kernel_launch(void* const* d_in, const int* in_sizes, int n_in,
                              void* d_out, int out_size, void* d_ws, size_t ws_size,
                              hipStream_t stream)
{
    const float* xs = (const float*)d_in[0];
    const void* xs_len = d_in[1];
    float* out = (float*)d_out;
    unsigned* table = (unsigned*)d_ws;       // [0,2112) u32 used; area = 16 KiB
    float* ws = (float*)d_ws;                // partial slots start at float4 idx SLOT0_F4

    mp_setup<<<dim3(1), dim3(1024), 0, stream>>>(xs_len, table);
    mp_partial<<<dim3(NGRID), dim3(256), 0, stream>>>(xs, table, ws);
    mp_reduce<<<dim3(B_ * 4), dim3(256), 0, stream>>>(ws, table, out);
}